// Round 1
// baseline (6820.786 us; speedup 1.0000x reference)
//
#include <hip/hip_runtime.h>

#define PER  149796
#define HDIM 64
#define EDIM 32
#define MAXC 16

__device__ __forceinline__ float sigf(float x){ return 1.0f/(1.0f+__expf(-x)); }
__device__ __forceinline__ float tanh_f(float x){
  float ax = fabsf(x);
  float e  = __expf(-2.0f*ax);
  float t  = (1.0f - e)/(1.0f + e);
  return x < 0.0f ? -t : t;
}

// ---------------- leaf level (depth 7): no children ----------------
__global__ __launch_bounds__(256,1) void leaf_kernel(
    const int* __restrict__ tok, const float* __restrict__ emb,
    const float* __restrict__ Wiou, const float* __restrict__ biou,
    float* __restrict__ hC, float* __restrict__ cC)
{
  int j = blockIdx.x*blockDim.x + threadIdx.x;
  if (j >= PER) return;
  int g = 1 + 6*PER + j;
  int t = tok[g];
  float x[EDIM];
  const float4* e4 = (const float4*)(emb + (size_t)t*EDIM);
  #pragma unroll
  for (int q=0;q<EDIM/4;q++){ float4 v=e4[q]; x[4*q]=v.x; x[4*q+1]=v.y; x[4*q+2]=v.z; x[4*q+3]=v.w; }
  float4* hr = (float4*)(hC + (size_t)j*HDIM);
  float4* cr = (float4*)(cC + (size_t)j*HDIM);
  for (int mq=0; mq<16; mq++){
    float cc[4], hh[4];
    #pragma unroll
    for (int r=0;r<4;r++){
      int m = mq*4+r;
      float ai=biou[m], ao=biou[HDIM+m], au=biou[2*HDIM+m];
      #pragma unroll
      for (int e=0;e<EDIM;e++){
        float xe = x[e];
        ai += Wiou[(size_t)m*EDIM+e]*xe;
        ao += Wiou[(size_t)(HDIM+m)*EDIM+e]*xe;
        au += Wiou[(size_t)(2*HDIM+m)*EDIM+e]*xe;
      }
      float c = sigf(ai)*tanh_f(au);
      cc[r]=c; hh[r]=sigf(ao)*tanh_f(c);
    }
    cr[mq] = make_float4(cc[0],cc[1],cc[2],cc[3]);
    hr[mq] = make_float4(hh[0],hh[1],hh[2],hh[3]);
  }
}

// ---------------- prep: wf rows for parent level + zero child counts ----------------
__global__ __launch_bounds__(256,1) void prep_kernel(
    const int* __restrict__ tok, const float* __restrict__ emb,
    const float* __restrict__ Wf, const float* __restrict__ bf,
    float* __restrict__ wf, int* __restrict__ counts, int loff, int count)
{
  int j = blockIdx.x*blockDim.x + threadIdx.x;
  if (j >= count) return;
  counts[j] = 0;
  int t = tok[loff + j];
  float x[EDIM];
  const float4* e4 = (const float4*)(emb + (size_t)t*EDIM);
  #pragma unroll
  for (int q=0;q<EDIM/4;q++){ float4 v=e4[q]; x[4*q]=v.x; x[4*q+1]=v.y; x[4*q+2]=v.z; x[4*q+3]=v.w; }
  float4* wr = (float4*)(wf + (size_t)j*HDIM);
  for (int mq=0; mq<16; mq++){
    float w[4];
    #pragma unroll
    for (int r=0;r<4;r++){
      int m = mq*4+r;
      float a = bf[m];
      #pragma unroll
      for (int e=0;e<EDIM;e++) a += Wf[(size_t)m*EDIM+e]*x[e];
      w[r]=a;
    }
    wr[mq] = make_float4(w[0],w[1],w[2],w[3]);
  }
}

// ---------------- build child lists (1 int atomic per child) ----------------
__global__ __launch_bounds__(256,1) void build_kernel(
    const int* __restrict__ parent, int* __restrict__ counts, int* __restrict__ list,
    int coff, int poff)
{
  int jc = blockIdx.x*blockDim.x + threadIdx.x;
  if (jc >= PER) return;
  int jp = parent[coff+jc] - poff;
  int slot = atomicAdd(&counts[jp], 1);
  if (slot < MAXC) list[jp*MAXC + slot] = jc;
}

// ---------------- edge: per-child f ⊙ c rows ----------------
__global__ __launch_bounds__(256,1) void edge_kernel(
    const int* __restrict__ parent, const float* __restrict__ Uf,
    const float* __restrict__ wf, const float* __restrict__ hP, const float* __restrict__ cP,
    float* __restrict__ fch, int coff, int poff)
{
  int jc = blockIdx.x*blockDim.x + threadIdx.x;
  if (jc >= PER) return;
  int jp = parent[coff+jc] - poff;
  float hk[HDIM];
  const float4* h4 = (const float4*)(hP + (size_t)jc*HDIM);
  #pragma unroll
  for (int q=0;q<16;q++){ float4 v=h4[q]; hk[4*q]=v.x; hk[4*q+1]=v.y; hk[4*q+2]=v.z; hk[4*q+3]=v.w; }
  const float4* w4 = (const float4*)(wf + (size_t)jp*HDIM);
  const float4* c4 = (const float4*)(cP + (size_t)jc*HDIM);
  float4* o4 = (float4*)(fch + (size_t)jc*HDIM);
  for (int mq=0; mq<16; mq++){
    float4 wv = w4[mq], cv = c4[mq];
    float wfa[4] = {wv.x, wv.y, wv.z, wv.w};
    float cva[4] = {cv.x, cv.y, cv.z, cv.w};
    float o[4];
    #pragma unroll
    for (int r=0;r<4;r++){
      int m = mq*4+r;
      float uf = 0.f;
      #pragma unroll
      for (int k=0;k<HDIM;k++) uf += Uf[(size_t)m*HDIM+k]*hk[k];
      o[r] = sigf(wfa[r] + uf) * cva[r];
    }
    o4[mq] = make_float4(o[0],o[1],o[2],o[3]);
  }
}

// ---------------- node: gather children (no atomics), full cell update ----------------
__global__ __launch_bounds__(256,1) void node_kernel(
    const int* __restrict__ tok, const float* __restrict__ emb,
    const float* __restrict__ Wiou, const float* __restrict__ biou, const float* __restrict__ Uiou,
    const int* __restrict__ counts, const int* __restrict__ list,
    const float* __restrict__ fch, const float* __restrict__ hP,
    float* __restrict__ hC, float* __restrict__ cC, int loff)
{
  int j = blockIdx.x*blockDim.x + threadIdx.x;
  if (j >= PER) return;
  float hs[HDIM], fa[HDIM];
  #pragma unroll
  for (int k=0;k<HDIM;k++){ hs[k]=0.f; fa[k]=0.f; }
  int nc = counts[j]; if (nc > MAXC) nc = MAXC;
  for (int s=0; s<nc; s++){
    int jc = list[j*MAXC + s];
    const float4* h4 = (const float4*)(hP  + (size_t)jc*HDIM);
    const float4* f4 = (const float4*)(fch + (size_t)jc*HDIM);
    #pragma unroll
    for (int q=0;q<16;q++){
      float4 hv=h4[q], fv=f4[q];
      hs[4*q]+=hv.x; hs[4*q+1]+=hv.y; hs[4*q+2]+=hv.z; hs[4*q+3]+=hv.w;
      fa[4*q]+=fv.x; fa[4*q+1]+=fv.y; fa[4*q+2]+=fv.z; fa[4*q+3]+=fv.w;
    }
  }
  int t = tok[loff + j];
  float x[EDIM];
  const float4* e4 = (const float4*)(emb + (size_t)t*EDIM);
  #pragma unroll
  for (int q=0;q<EDIM/4;q++){ float4 v=e4[q]; x[4*q]=v.x; x[4*q+1]=v.y; x[4*q+2]=v.z; x[4*q+3]=v.w; }
  float4* hr = (float4*)(hC + (size_t)j*HDIM);
  float4* cr = (float4*)(cC + (size_t)j*HDIM);
  #pragma unroll
  for (int mq=0; mq<16; mq++){
    float cc[4], hh[4];
    #pragma unroll
    for (int r=0;r<4;r++){
      int m = mq*4+r;
      float ai=biou[m], ao=biou[HDIM+m], au=biou[2*HDIM+m];
      #pragma unroll
      for (int e=0;e<EDIM;e++){
        float xe = x[e];
        ai += Wiou[(size_t)m*EDIM+e]*xe;
        ao += Wiou[(size_t)(HDIM+m)*EDIM+e]*xe;
        au += Wiou[(size_t)(2*HDIM+m)*EDIM+e]*xe;
      }
      #pragma unroll
      for (int k=0;k<HDIM;k++){
        float hv = hs[k];
        ai += Uiou[(size_t)m*HDIM+k]*hv;
        ao += Uiou[(size_t)(HDIM+m)*HDIM+k]*hv;
        au += Uiou[(size_t)(2*HDIM+m)*HDIM+k]*hv;
      }
      float c = sigf(ai)*tanh_f(au) + fa[m];
      cc[r]=c; hh[r]=sigf(ao)*tanh_f(c);
    }
    cr[mq] = make_float4(cc[0],cc[1],cc[2],cc[3]);
    hr[mq] = make_float4(hh[0],hh[1],hh[2],hh[3]);
  }
}

// ---------------- root: reduce all level-1 children ----------------
__global__ __launch_bounds__(256,1) void rootred_kernel(
    const float* __restrict__ fch, const float* __restrict__ hP, float* __restrict__ rootacc)
{
  int t = blockIdx.x*blockDim.x + threadIdx.x;
  int m = t & 63;
  int j0 = t >> 6;
  int jstep = (gridDim.x*blockDim.x) >> 6;
  float af=0.f, ah=0.f;
  for (int j=j0; j<PER; j+=jstep){
    af += fch[(size_t)j*HDIM + m];
    ah += hP [(size_t)j*HDIM + m];
  }
  __shared__ float red[256];
  red[threadIdx.x]=af; __syncthreads();
  if (threadIdx.x < 64) atomicAdd(&rootacc[m],      red[m]+red[64+m]+red[128+m]+red[192+m]);
  __syncthreads();
  red[threadIdx.x]=ah; __syncthreads();
  if (threadIdx.x < 64) atomicAdd(&rootacc[64+m],   red[m]+red[64+m]+red[128+m]+red[192+m]);
}

__global__ void rootnode_kernel(
    const int* __restrict__ tok, const float* __restrict__ emb,
    const float* __restrict__ Wiou, const float* __restrict__ biou, const float* __restrict__ Uiou,
    const float* __restrict__ rootacc, float* __restrict__ out)
{
  int m = threadIdx.x;
  if (m >= HDIM) return;
  int t = tok[0];
  float ai=biou[m], ao=biou[HDIM+m], au=biou[2*HDIM+m];
  for (int e=0;e<EDIM;e++){
    float xe = emb[(size_t)t*EDIM+e];
    ai += Wiou[(size_t)m*EDIM+e]*xe;
    ao += Wiou[(size_t)(HDIM+m)*EDIM+e]*xe;
    au += Wiou[(size_t)(2*HDIM+m)*EDIM+e]*xe;
  }
  for (int k=0;k<HDIM;k++){
    float hv = rootacc[64+k];
    ai += Uiou[(size_t)m*HDIM+k]*hv;
    ao += Uiou[(size_t)(HDIM+m)*HDIM+k]*hv;
    au += Uiou[(size_t)(2*HDIM+m)*HDIM+k]*hv;
  }
  float c = sigf(ai)*tanh_f(au) + rootacc[m];
  out[m] = sigf(ao)*tanh_f(c);
}

extern "C" void kernel_launch(void* const* d_in, const int* in_sizes, int n_in,
                              void* d_out, int out_size, void* d_ws, size_t ws_size,
                              hipStream_t stream)
{
  const int*   tok    = (const int*)d_in[0];
  const int*   parent = (const int*)d_in[1];
  const float* emb    = (const float*)d_in[4];
  const float* Wiou   = (const float*)d_in[5];
  const float* biou   = (const float*)d_in[6];
  const float* Uiou   = (const float*)d_in[7];
  const float* Wf     = (const float*)d_in[8];
  const float* bf     = (const float*)d_in[9];
  const float* Uf     = (const float*)d_in[10];
  float* out = (float*)d_out;

  float* ws = (float*)d_ws;
  size_t SZ = (size_t)PER*HDIM;
  float* hA   = ws;
  float* cA   = ws + SZ;
  float* hB   = ws + 2*SZ;
  float* cB   = ws + 3*SZ;
  float* wf   = ws + 4*SZ;
  float* fch  = ws + 5*SZ;
  float* rootacc = ws + 6*SZ;                 // 128 floats
  int* counts = (int*)(ws + 6*SZ + 128);      // PER ints
  int* list   = counts + PER;                 // PER*MAXC ints

  const int B = 256;
  const int gPER = (PER + B - 1)/B;

  // depth 7 (leaves) -> A
  leaf_kernel<<<gPER, B, 0, stream>>>(tok, emb, Wiou, biou, hA, cA);

  float* hPrev=hA; float* cPrev=cA; float* hCur=hB; float* cCur=cB;
  for (int d=6; d>=1; --d){
    int poff = 1 + (d-1)*PER;
    int coff = 1 + d*PER;
    prep_kernel <<<gPER, B, 0, stream>>>(tok, emb, Wf, bf, wf, counts, poff, PER);
    build_kernel<<<gPER, B, 0, stream>>>(parent, counts, list, coff, poff);
    edge_kernel <<<gPER, B, 0, stream>>>(parent, Uf, wf, hPrev, cPrev, fch, coff, poff);
    node_kernel <<<gPER, B, 0, stream>>>(tok, emb, Wiou, biou, Uiou, counts, list, fch,
                                         hPrev, hCur, cCur, poff);
    float* th=hPrev; hPrev=hCur; hCur=th;
    float* tc=cPrev; cPrev=cCur; cCur=tc;
  }

  // depth 0 (root): all level-1 nodes are its children
  prep_kernel<<<1, B, 0, stream>>>(tok, emb, Wf, bf, wf, counts, 0, 1);
  hipMemsetAsync(rootacc, 0, 128*sizeof(float), stream);
  edge_kernel<<<gPER, B, 0, stream>>>(parent, Uf, wf, hPrev, cPrev, fch, 1, 0);
  rootred_kernel<<<256, B, 0, stream>>>(fch, hPrev, rootacc);
  rootnode_kernel<<<1, 64, 0, stream>>>(tok, emb, Wiou, biou, Uiou, rootacc, out);
}

// Round 2
// 1365.090 us; speedup vs baseline: 4.9966x; 4.9966x over previous
//
#include <hip/hip_runtime.h>

#define PER  149796
#define HDIM 64
#define EDIM 32
#define MAXC 16
#define NIOU 192

__device__ __forceinline__ float sigf(float x){ return 1.0f/(1.0f+__expf(-x)); }
__device__ __forceinline__ float tanh_f(float x){
  float ax = fabsf(x);
  float e  = __expf(-2.0f*ax);
  float t  = (1.0f - e)/(1.0f + e);
  return x < 0.0f ? -t : t;
}

// ---- tables: embWiou[v][192] = biou + Wiou.emb[v]; embWf[v][64] = bf + Wf.emb[v]
__global__ __launch_bounds__(256) void table_kernel(
    const float* __restrict__ emb, const float* __restrict__ Wiou, const float* __restrict__ biou,
    const float* __restrict__ Wf, const float* __restrict__ bf,
    float* __restrict__ embWiou, float* __restrict__ embWf)
{
  int v = blockIdx.x;           // 0..1023
  int m = threadIdx.x;          // 0..255 : 0..191 -> iou, 192..255 -> f
  const float* x = emb + (size_t)v*EDIM;   // v uniform -> scalar loads
  if (m < NIOU){
    float a = biou[m];
    #pragma unroll
    for (int e=0;e<EDIM;e++) a += Wiou[m*EDIM+e]*x[e];
    embWiou[(size_t)v*NIOU + m] = a;
  } else {
    int mm = m - NIOU;
    float a = bf[mm];
    #pragma unroll
    for (int e=0;e<EDIM;e++) a += Wf[mm*EDIM+e]*x[e];
    embWf[(size_t)v*HDIM + mm] = a;
  }
}

// ---- transpose U matrices so weight loads are coalesced: UT[k][m] = U[m][k]
__global__ void transpose_kernel(const float* __restrict__ Uiou, const float* __restrict__ Uf,
                                 float* __restrict__ UiouT, float* __restrict__ UfT)
{
  for (int i = threadIdx.x; i < NIOU*HDIM; i += 256){
    int gm = i / HDIM, k = i % HDIM;
    UiouT[k*NIOU + gm] = Uiou[i];
  }
  for (int i = threadIdx.x; i < HDIM*HDIM; i += 256){
    int mm = i / HDIM, k = i % HDIM;
    UfT[k*HDIM + mm] = Uf[i];
  }
}

// ---- leaves (depth 7): pure elementwise from table
__global__ __launch_bounds__(256) void leaf_kernel(
    const int* __restrict__ tok, const float* __restrict__ embWiou,
    float* __restrict__ hC, float* __restrict__ cC)
{
  int gid = blockIdx.x*blockDim.x + threadIdx.x;   // over PER*16 float4 groups
  if (gid >= PER*16) return;
  int j = gid >> 4, sub = gid & 15;
  int t = tok[1 + 6*PER + j];
  const float* row = embWiou + (size_t)t*NIOU;
  float4 i4 = *(const float4*)(row + sub*4);
  float4 o4 = *(const float4*)(row + 64 + sub*4);
  float4 u4 = *(const float4*)(row + 128 + sub*4);
  float4 cv, hv;
  cv.x = sigf(i4.x)*tanh_f(u4.x); hv.x = sigf(o4.x)*tanh_f(cv.x);
  cv.y = sigf(i4.y)*tanh_f(u4.y); hv.y = sigf(o4.y)*tanh_f(cv.y);
  cv.z = sigf(i4.z)*tanh_f(u4.z); hv.z = sigf(o4.z)*tanh_f(cv.z);
  cv.w = sigf(i4.w)*tanh_f(u4.w); hv.w = sigf(o4.w)*tanh_f(cv.w);
  *(float4*)(cC + (size_t)j*HDIM + sub*4) = cv;
  *(float4*)(hC + (size_t)j*HDIM + sub*4) = hv;
}

// ---- child lists (1 int atomic per child); counts pre-zeroed by memset
__global__ __launch_bounds__(256) void build_kernel(
    const int* __restrict__ parent, int* __restrict__ counts, int* __restrict__ list,
    int coff, int poff)
{
  int jc = blockIdx.x*blockDim.x + threadIdx.x;
  if (jc >= PER) return;
  int jp = parent[coff+jc] - poff;
  int slot = atomicAdd(&counts[jp], 1);
  if (slot < MAXC) list[jp*MAXC + slot] = jc;
}

// ---- fch: wave per child, Uf row m stationary in lane-m registers
__global__ __launch_bounds__(256,4) void fch_kernel(
    const int* __restrict__ tok, const int* __restrict__ parent,
    const float* __restrict__ embWf, const float* __restrict__ UfT,
    const float* __restrict__ hP, const float* __restrict__ cP,
    float* __restrict__ fch, int coff)
{
  int m  = threadIdx.x & 63;
  int wq = __builtin_amdgcn_readfirstlane(threadIdx.x >> 6);
  int wid = blockIdx.x*4 + wq;
  int nw  = gridDim.x*4;
  float w[HDIM];
  #pragma unroll
  for (int k=0;k<HDIM;k++) w[k] = UfT[k*HDIM + m];      // coalesced, once per wave
  for (int jc = wid; jc < PER; jc += nw){
    int jp = parent[coff + jc];                          // scalar
    int t  = tok[jp];                                    // scalar
    float acc = embWf[(size_t)t*HDIM + m];               // coalesced gather
    const float* hrow = hP + (size_t)jc*HDIM;            // wave-uniform row
    #pragma unroll
    for (int k=0;k<HDIM;k++) acc += w[k]*hrow[k];
    float c = cP[(size_t)jc*HDIM + m];
    fch[(size_t)jc*HDIM + m] = sigf(acc)*c;
  }
}

// ---- node: wave per parent node; Uiou columns stationary (192 VGPRs/lane)
__global__ __launch_bounds__(256,2) void node_kernel(
    const int* __restrict__ tok, const float* __restrict__ embWiou,
    const float* __restrict__ UiouT,
    const int* __restrict__ counts, const int* __restrict__ list,
    const float* __restrict__ fch, const float* __restrict__ hP,
    float* __restrict__ hC, float* __restrict__ cC, int loff)
{
  int m  = threadIdx.x & 63;
  int wq = __builtin_amdgcn_readfirstlane(threadIdx.x >> 6);
  int wid = blockIdx.x*4 + wq;
  int nw  = gridDim.x*4;
  float wI[HDIM], wO[HDIM], wU[HDIM];
  #pragma unroll
  for (int k=0;k<HDIM;k++){
    wI[k] = UiouT[k*NIOU       + m];
    wO[k] = UiouT[k*NIOU + 64  + m];
    wU[k] = UiouT[k*NIOU + 128 + m];
  }
  for (int j = wid; j < PER; j += nw){
    int t = tok[loff + j];                               // scalar
    const float* trow = embWiou + (size_t)t*NIOU;
    float ai = trow[m], ao = trow[64+m], au = trow[128+m];
    float fa = 0.f;
    int nc = counts[j]; if (nc > MAXC) nc = MAXC;        // scalar
    for (int s=0; s<nc; s++){
      int jc = list[j*MAXC + s];                         // scalar
      fa += fch[(size_t)jc*HDIM + m];                    // coalesced
      const float* hrow = hP + (size_t)jc*HDIM;          // wave-uniform row
      #pragma unroll
      for (int k=0;k<HDIM;k++){
        float hv = hrow[k];
        ai += wI[k]*hv; ao += wO[k]*hv; au += wU[k]*hv;
      }
    }
    float c = sigf(ai)*tanh_f(au) + fa;
    float h = sigf(ao)*tanh_f(c);
    cC[(size_t)j*HDIM + m] = c;
    hC[(size_t)j*HDIM + m] = h;
  }
}

// ---- root reduction over all level-1 children
__global__ __launch_bounds__(256,1) void rootred_kernel(
    const float* __restrict__ fch, const float* __restrict__ hP, float* __restrict__ rootacc)
{
  int t = blockIdx.x*blockDim.x + threadIdx.x;
  int m = t & 63;
  int j0 = t >> 6;
  int jstep = (gridDim.x*blockDim.x) >> 6;
  float af=0.f, ah=0.f;
  for (int j=j0; j<PER; j+=jstep){
    af += fch[(size_t)j*HDIM + m];
    ah += hP [(size_t)j*HDIM + m];
  }
  __shared__ float red[256];
  red[threadIdx.x]=af; __syncthreads();
  if (threadIdx.x < 64) atomicAdd(&rootacc[m],    red[m]+red[64+m]+red[128+m]+red[192+m]);
  __syncthreads();
  red[threadIdx.x]=ah; __syncthreads();
  if (threadIdx.x < 64) atomicAdd(&rootacc[64+m], red[m]+red[64+m]+red[128+m]+red[192+m]);
}

__global__ void rootnode_kernel(
    const int* __restrict__ tok, const float* __restrict__ emb,
    const float* __restrict__ Wiou, const float* __restrict__ biou, const float* __restrict__ Uiou,
    const float* __restrict__ rootacc, float* __restrict__ out)
{
  int m = threadIdx.x;
  if (m >= HDIM) return;
  int t = tok[0];
  float ai=biou[m], ao=biou[HDIM+m], au=biou[2*HDIM+m];
  for (int e=0;e<EDIM;e++){
    float xe = emb[(size_t)t*EDIM+e];
    ai += Wiou[(size_t)m*EDIM+e]*xe;
    ao += Wiou[(size_t)(HDIM+m)*EDIM+e]*xe;
    au += Wiou[(size_t)(2*HDIM+m)*EDIM+e]*xe;
  }
  for (int k=0;k<HDIM;k++){
    float hv = rootacc[64+k];
    ai += Uiou[(size_t)m*HDIM+k]*hv;
    ao += Uiou[(size_t)(HDIM+m)*HDIM+k]*hv;
    au += Uiou[(size_t)(2*HDIM+m)*HDIM+k]*hv;
  }
  float c = sigf(ai)*tanh_f(au) + rootacc[m];
  out[m] = sigf(ao)*tanh_f(c);
}

extern "C" void kernel_launch(void* const* d_in, const int* in_sizes, int n_in,
                              void* d_out, int out_size, void* d_ws, size_t ws_size,
                              hipStream_t stream)
{
  const int*   tok    = (const int*)d_in[0];
  const int*   parent = (const int*)d_in[1];
  const float* emb    = (const float*)d_in[4];
  const float* Wiou   = (const float*)d_in[5];
  const float* biou   = (const float*)d_in[6];
  const float* Uiou   = (const float*)d_in[7];
  const float* Wf     = (const float*)d_in[8];
  const float* bf     = (const float*)d_in[9];
  const float* Uf     = (const float*)d_in[10];
  float* out = (float*)d_out;

  float* ws = (float*)d_ws;
  size_t SZ = (size_t)PER*HDIM;
  float* hA      = ws;
  float* cA      = ws + SZ;
  float* hB      = ws + 2*SZ;
  float* cB      = ws + 3*SZ;
  float* fch     = ws + 4*SZ;
  float* embWiou = ws + 5*SZ;                 // 1024*192
  float* embWf   = embWiou + 1024*NIOU;       // 1024*64
  float* UiouT   = embWf + 1024*HDIM;         // 192*64
  float* UfT     = UiouT + NIOU*HDIM;         // 64*64
  float* rootacc = UfT + HDIM*HDIM;           // 128
  int*   counts  = (int*)(rootacc + 128);     // PER
  int*   list    = counts + PER;              // PER*MAXC

  const int B = 256;
  const int gPER   = (PER + B - 1)/B;
  const int gLEAF  = (PER*16 + B - 1)/B;

  table_kernel<<<1024, B, 0, stream>>>(emb, Wiou, biou, Wf, bf, embWiou, embWf);
  transpose_kernel<<<1, B, 0, stream>>>(Uiou, Uf, UiouT, UfT);

  // depth 7 (leaves) -> A
  leaf_kernel<<<gLEAF, B, 0, stream>>>(tok, embWiou, hA, cA);

  float* hPrev=hA; float* cPrev=cA; float* hCur=hB; float* cCur=cB;
  for (int d=6; d>=1; --d){
    int poff = 1 + (d-1)*PER;
    int coff = 1 + d*PER;
    hipMemsetAsync(counts, 0, (size_t)PER*sizeof(int), stream);
    build_kernel<<<gPER, B, 0, stream>>>(parent, counts, list, coff, poff);
    fch_kernel  <<<1024, B, 0, stream>>>(tok, parent, embWf, UfT, hPrev, cPrev, fch, coff);
    node_kernel <<<512,  B, 0, stream>>>(tok, embWiou, UiouT, counts, list, fch,
                                         hPrev, hCur, cCur, poff);
    float* th=hPrev; hPrev=hCur; hCur=th;
    float* tc=cPrev; cPrev=cCur; cCur=tc;
  }

  // depth 0 (root): all level-1 nodes are its children
  hipMemsetAsync(rootacc, 0, 128*sizeof(float), stream);
  fch_kernel<<<1024, B, 0, stream>>>(tok, parent, embWf, UfT, hPrev, cPrev, fch, 1);
  rootred_kernel<<<256, B, 0, stream>>>(fch, hPrev, rootacc);
  rootnode_kernel<<<1, 64, 0, stream>>>(tok, emb, Wiou, biou, Uiou, rootacc, out);
}